// Round 1
// 1106.883 us; speedup vs baseline: 1.1119x; 1.1119x over previous
//
#include <hip/hip_runtime.h>
#include <hip/hip_bf16.h>

typedef __attribute__((ext_vector_type(8))) short short8;
typedef __attribute__((ext_vector_type(16))) float f32x16;
typedef __attribute__((ext_vector_type(4))) unsigned int u32x4;
typedef unsigned short u16;
typedef unsigned int u32;

#define B_ROWS 4096
#define D_KEYS 50000
#define DPAD   50048
#define KDIM   64
#define NCOL   1000
#define NPAD   1024
#define SCALEF 300000.0f
#define EPSF   1e-4f
#define NCHUNKS 782          // DPAD/64
#define NEG2S  (-2.0f / SCALEF)
#define DZ     4

// ---------------- helpers ----------------

__device__ __forceinline__ u16 f2bf(float f) {          // RNE float->bf16
    u32 u = __builtin_bit_cast(u32, f);
    u = (u + 0x7FFFu + ((u >> 16) & 1u)) >> 16;
    return (u16)u;
}

__device__ __forceinline__ u32 pack2(float a, float b) { // 2xf32 -> packed bf16x2
    __hip_bfloat162 r = __float22bfloat162_rn(make_float2(a, b));
    u32 pk;
    __builtin_memcpy(&pk, &r, 4);
    return pk;
}

__device__ __forceinline__ void glds16(const void* g, void* l) {
    __builtin_amdgcn_global_load_lds(
        (const __attribute__((address_space(1))) u32*)(uintptr_t)g,
        (__attribute__((address_space(3))) u32*)(uintptr_t)l, 16, 0, 0);
}

// ---------------- pre-pass kernels ----------------

__global__ void prep_x_kernel(const float* __restrict__ x,
                              u16* __restrict__ x_bf, float* __restrict__ xn2) {
    int row = (blockIdx.x * blockDim.x + threadIdx.x) >> 6;
    int lane = threadIdx.x & 63;
    if (row >= B_ROWS) return;
    float v = x[(size_t)row * KDIM + lane];
    x_bf[(size_t)row * KDIM + lane] = f2bf(v);
    float s = v * v;
    #pragma unroll
    for (int off = 32; off > 0; off >>= 1) s += __shfl_down(s, off, 64);
    if (lane == 0) xn2[row] = s * (1.0f / SCALEF);
}

__global__ void prep_keys_kernel(const float* __restrict__ keys,
                                 u16* __restrict__ keys_bf, float* __restrict__ kn2) {
    int row = (blockIdx.x * blockDim.x + threadIdx.x) >> 6;
    int lane = threadIdx.x & 63;
    if (row >= DPAD) return;
    float v = (row < D_KEYS) ? keys[(size_t)row * KDIM + lane] : 0.f;
    keys_bf[(size_t)row * KDIM + lane] = f2bf(v);
    float s = v * v;
    #pragma unroll
    for (int off = 32; off > 0; off >>= 1) s += __shfl_down(s, off, 64);
    if (lane == 0) kn2[row] = s * (1.0f / SCALEF) + EPSF;
}

// V (50000x1000 f32) -> Vt (1024x50048 bf16, d contiguous), zero-padded
__global__ void prep_v_kernel(const float* __restrict__ V, u16* __restrict__ vt) {
    __shared__ float tile[64][65];
    const int d0 = blockIdx.x * 64;
    const int n0 = blockIdx.y * 64;
    const int t = threadIdx.x;
    #pragma unroll
    for (int p = 0; p < 16; p++) {
        int idx = p * 256 + t;
        int di = idx >> 6, nj = idx & 63;
        int d = d0 + di, n = n0 + nj;
        tile[di][nj] = (d < D_KEYS && n < NCOL) ? V[(size_t)d * NCOL + n] : 0.f;
    }
    __syncthreads();
    #pragma unroll
    for (int p = 0; p < 8; p++) {
        int idx = p * 256 + t;
        int ni = idx >> 5, dp = idx & 31;          // d-pair
        u32 pk = pack2(tile[2 * dp][ni], tile[2 * dp + 1][ni]);
        *(u32*)&vt[(size_t)(n0 + ni) * DPAD + d0 + 2 * dp] = pk;
    }
}

__global__ void zero_kernel(float4* __restrict__ p, int n4) {
    for (int i = blockIdx.x * 256 + threadIdx.x; i < n4; i += gridDim.x * 256)
        p[i] = make_float4(0.f, 0.f, 0.f, 0.f);
}

// ---------------- main MFMA kernel ----------------
// grid (8 n-tiles, 16 b-tiles, DZ d-splits), 256 threads (4 waves)
// BM=256 (wave owns 64 b-rows = 2 b-groups), BN=128, D-chunk 64.
// Double-buffered LDS: stage chunk c+1 while computing chunk c; the single
// __syncthreads() per chunk performs the vmcnt drain AFTER compute has hidden
// the global_load_lds latency.
// Each af/vf LDS read now feeds 2 MFMAs (bg=0/1) -> LDS reads & bank-conflict
// cycles per FLOP halved vs BM=128 version.
__global__ __launch_bounds__(256, 2)
void varkeys_mfma4_kernel(const u16* __restrict__ x_bf,
                          const u16* __restrict__ keys_bf,
                          const u16* __restrict__ vt_bf,
                          const float* __restrict__ xn2,
                          const float* __restrict__ kn2,
                          float* __restrict__ partial,
                          int atomic_mode) {
    __shared__ alignas(16) u16 keys_lds[2][64 * 64];    // [buf][d][k], 16B-swizzled
    __shared__ alignas(16) u16 v_lds[2][128 * 64];      // [buf][n][d], 16B-swizzled
    __shared__ alignas(16) float kn_lds[2][256];        // only [0..63] meaningful

    const int t = threadIdx.x;
    const int w = t >> 6;
    const int lane = t & 63;
    const int half = lane >> 5;            // h
    const int l31 = lane & 31;

    const int n0 = blockIdx.x * 128;
    const int b0 = blockIdx.y * 256;
    const int bz = blockIdx.z;
    const int c_begin = (bz * NCHUNKS) / DZ;
    const int c_end = ((bz + 1) * NCHUNKS) / DZ;

    // x fragments (scores B operand) pinned in VGPRs, 2 b-groups per wave
    float xnv[2];
    short8 xfrag[2][4];
    #pragma unroll
    for (int bg = 0; bg < 2; bg++) {
        int brow = b0 + 64 * w + 32 * bg + l31;
        xnv[bg] = xn2[brow];
        #pragma unroll
        for (int kk = 0; kk < 4; kk++)
            xfrag[bg][kk] = *(const short8*)(x_bf + (size_t)brow * KDIM + kk * 16 + half * 8);
    }

    f32x16 acc[2][4];
    #pragma unroll
    for (int bg = 0; bg < 2; bg++)
        #pragma unroll
        for (int nt = 0; nt < 4; nt++)
            #pragma unroll
            for (int i = 0; i < 16; i++) acc[bg][nt][i] = 0.f;

    const int srow = lane >> 3;
    const int cg = (lane & 7) ^ srow;      // swizzled 16B chunk for staging

    // stage chunk c (keys 8KB + Vt 16KB + kn 256B) into buffer bi, direct-to-LDS
    auto stage = [&](int c, int bi) {
        const int d0 = c * 64;
        #pragma unroll
        for (int q = 0; q < 2; q++) {
            int i = w * 2 + q;
            glds16(keys_bf + (size_t)(d0 + 8 * i + srow) * KDIM + cg * 8,
                   &keys_lds[bi][i * 512]);
        }
        #pragma unroll
        for (int q = 0; q < 4; q++) {
            int i = w * 4 + q;
            glds16(vt_bf + (size_t)(n0 + 8 * i + srow) * DPAD + d0 + cg * 8,
                   &v_lds[bi][i * 512]);
        }
        if (w == 0)   // wave-level: 64 lanes x 16B = 1KB; lanes >=16 write junk
            glds16(kn2 + d0 + lane * 4, &kn_lds[bi][0]);   // into [64..255], unused
    };

    stage(c_begin, 0);
    __syncthreads();          // drains vmcnt(0): buffer 0 ready

    int cur = 0;
    for (int c = c_begin; c < c_end; c++) {
        if (c + 1 < c_end) stage(c + 1, cur ^ 1);   // issue early, no wait
        const int d0 = c * 64;
        const bool tail = (d0 + 64 > D_KEYS);
        const u16* klds = &keys_lds[cur][0];
        const u16* vlds = &v_lds[cur][0];
        const float* knl = &kn_lds[cur][0];

        #pragma unroll
        for (int dt = 0; dt < 2; dt++) {
            // ---- scores MFMA: m=d (A=keys, shared), n=b (B=x, per b-group) ----
            f32x16 s[2];
            #pragma unroll
            for (int bg = 0; bg < 2; bg++)
                #pragma unroll
                for (int i = 0; i < 16; i++) s[bg][i] = 0.f;
            const int dl = dt * 32 + l31;
            __builtin_amdgcn_s_setprio(1);
            #pragma unroll
            for (int kk = 0; kk < 4; kk++) {
                int cidx = kk * 2 + half;
                short8 af = *(const short8*)&klds[dl * 64 + ((cidx ^ (dl & 7)) * 8)];
                s[0] = __builtin_amdgcn_mfma_f32_32x32x16_bf16(af, xfrag[0][kk], s[0], 0, 0, 0);
                s[1] = __builtin_amdgcn_mfma_f32_32x32x16_bf16(af, xfrag[1][kk], s[1], 0, 0, 0);
            }
            __builtin_amdgcn_s_setprio(0);

            // ---- epilogue: dist -> rcp -> bf16 pairs P[bg][m][2] ----
            // lane's s[bg][r] = ker[d = dt*32 + (r&3)+8*(r>>2)+4*half][b = own bg row]
            u32 P[2][4][2];
            #pragma unroll
            for (int bg = 0; bg < 2; bg++) {
                #pragma unroll
                for (int m = 0; m < 4; m++) {
                    float kv[4];
                    #pragma unroll
                    for (int j = 0; j < 4; j++) {
                        int r = 4 * m + j;
                        int dloc = dt * 32 + 8 * m + 4 * half + j;
                        float dist = fmaf(s[bg][r], NEG2S, knl[dloc] + xnv[bg]);
                        kv[j] = __builtin_amdgcn_rcpf(dist);
                    }
                    if (tail) {
                        #pragma unroll
                        for (int j = 0; j < 4; j++)
                            if (d0 + dt * 32 + 8 * m + 4 * half + j >= D_KEYS) kv[j] = 0.f;
                    }
                    P[bg][m][0] = pack2(kv[0], kv[1]);
                    P[bg][m][1] = pack2(kv[2], kv[3]);
                }
            }

            // ---- C->A transform via half-wave exchange + PV MFMA ----
            #pragma unroll
            for (int q = 0; q < 2; q++) {
                short8 kfrag[2];
                #pragma unroll
                for (int bg = 0; bg < 2; bg++) {
                    u32 s0 = half ? P[bg][2 * q][0] : P[bg][2 * q + 1][0];
                    u32 s1 = half ? P[bg][2 * q][1] : P[bg][2 * q + 1][1];
                    u32 r0 = __shfl_xor((int)s0, 32, 64);
                    u32 r1 = __shfl_xor((int)s1, 32, 64);
                    u32x4 fr;
                    fr.x = half ? r0 : P[bg][2 * q][0];
                    fr.y = half ? r1 : P[bg][2 * q][1];
                    fr.z = half ? P[bg][2 * q + 1][0] : r0;
                    fr.w = half ? P[bg][2 * q + 1][1] : r1;
                    kfrag[bg] = __builtin_bit_cast(short8, fr);
                }
                const int kk = dt * 2 + q;
                const int cidx = kk * 2 + half;
                __builtin_amdgcn_s_setprio(1);
                #pragma unroll
                for (int nt = 0; nt < 4; nt++) {
                    int nl = nt * 32 + l31;
                    short8 vf = *(const short8*)&vlds[nl * 64 + ((cidx ^ (nl & 7)) * 8)];
                    acc[0][nt] = __builtin_amdgcn_mfma_f32_32x32x16_bf16(kfrag[0], vf, acc[0][nt], 0, 0, 0);
                    acc[1][nt] = __builtin_amdgcn_mfma_f32_32x32x16_bf16(kfrag[1], vf, acc[1][nt], 0, 0, 0);
                }
                __builtin_amdgcn_s_setprio(0);
            }
        }
        __syncthreads();   // drains vmcnt(0): next buffer staged; cur buffer free
        cur ^= 1;
    }

    // ---- output: per-dz partial buffer, or atomicAdd ----
    float* pout = atomic_mode ? partial
                              : partial + (size_t)bz * B_ROWS * NCOL;
    #pragma unroll
    for (int bg = 0; bg < 2; bg++) {
        #pragma unroll
        for (int nt = 0; nt < 4; nt++) {
            int n = n0 + nt * 32 + l31;
            if (n < NCOL) {
                #pragma unroll
                for (int r = 0; r < 16; r++) {
                    int brow = b0 + 64 * w + 32 * bg + (r & 3) + 8 * (r >> 2) + 4 * half;
                    if (atomic_mode)
                        atomicAdd(&pout[(size_t)brow * NCOL + n], acc[bg][nt][r]);
                    else
                        pout[(size_t)brow * NCOL + n] = acc[bg][nt][r];
                }
            }
        }
    }
}

// sum pcount partials, row-normalize
__global__ void finish_kernel(const float* __restrict__ partial, float* __restrict__ out,
                              int pcount) {
    const int b = blockIdx.x;
    const int t = threadIdx.x;
    float s = 0.f;
    for (int n = t; n < NCOL; n += 256) {
        float v = 0.f;
        for (int p = 0; p < pcount; p++)
            v += partial[(size_t)p * B_ROWS * NCOL + (size_t)b * NCOL + n];
        s += v;
    }
    __shared__ float red[4];
    #pragma unroll
    for (int off = 32; off > 0; off >>= 1) s += __shfl_down(s, off, 64);
    if ((t & 63) == 0) red[t >> 6] = s;
    __syncthreads();
    float inv = 1.0f / (red[0] + red[1] + red[2] + red[3]);
    for (int n = t; n < NCOL; n += 256) {
        float v = 0.f;
        for (int p = 0; p < pcount; p++)
            v += partial[(size_t)p * B_ROWS * NCOL + (size_t)b * NCOL + n];
        out[(size_t)b * NCOL + n] = v * inv;
    }
}

// ================= fallback fp32 path (round-1, known-correct) =================

__global__ void row_norm2_kernel(const float* __restrict__ a,
                                 float* __restrict__ out, int rows) {
    int wave = (blockIdx.x * blockDim.x + threadIdx.x) >> 6;
    int lane = threadIdx.x & 63;
    if (wave >= rows) return;
    float v = a[(size_t)wave * KDIM + lane];
    float s = v * v;
    #pragma unroll
    for (int off = 32; off > 0; off >>= 1) s += __shfl_down(s, off, 64);
    if (lane == 0) out[wave] = s;
}

#define DC 64
#define BT 64
#define NT 256

__global__ __launch_bounds__(256, 1)
void varkeys_main_kernel(const float* __restrict__ x,
                         const float* __restrict__ keys,
                         const float* __restrict__ V,
                         const float* __restrict__ xn,
                         const float* __restrict__ kn,
                         float* __restrict__ out) {
    __shared__ float x_lds[BT][68];
    __shared__ float keys_lds[DC][68];
    __shared__ float ker_lds[DC][65];
    __shared__ float xn_lds[BT];
    __shared__ float kn_lds[DC];
    const int t = threadIdx.x;
    const int n0 = blockIdx.x * NT;
    const int b0 = blockIdx.y * BT;
    for (int q = t; q < BT * 16; q += 256) {
        int row = q >> 4, c4 = q & 15;
        float4 v = *(const float4*)(x + (size_t)(b0 + row) * KDIM + c4 * 4);
        *(float4*)&x_lds[row][c4 * 4] = v;
    }
    if (t < BT) xn_lds[t] = xn[b0 + t];
    const int tn = t & 63;
    const int tb = t >> 6;
    const int tb16 = tb * 16;
    const int n4 = n0 + 4 * tn;
    const bool nvalid = (n4 < NCOL);
    float4 acc[16];
    #pragma unroll
    for (int j = 0; j < 16; j++) acc[j] = make_float4(0.f, 0.f, 0.f, 0.f);
    const int td = t & 15;
    const int tq = t >> 4;
    for (int d0 = 0; d0 < D_KEYS; d0 += DC) {
        const int dlim = min(DC, D_KEYS - d0);
        for (int q = t; q < DC * 16; q += 256) {
            int row = q >> 4, c4 = q & 15;
            if (d0 + row < D_KEYS) {
                float4 v = *(const float4*)(keys + (size_t)(d0 + row) * KDIM + c4 * 4);
                *(float4*)&keys_lds[row][c4 * 4] = v;
            }
        }
        if (t < DC) kn_lds[t] = (d0 + t < D_KEYS) ? kn[d0 + t] : 0.f;
        __syncthreads();
        {
            float4 s[4][4];
            #pragma unroll
            for (int i = 0; i < 4; i++)
                #pragma unroll
                for (int j = 0; j < 4; j++) s[i][j] = make_float4(0.f, 0.f, 0.f, 0.f);
            #pragma unroll
            for (int k4 = 0; k4 < 16; k4++) {
                float4 kv[4], xv[4];
                #pragma unroll
                for (int i = 0; i < 4; i++) kv[i] = *(const float4*)&keys_lds[td + 16 * i][k4 * 4];
                #pragma unroll
                for (int j = 0; j < 4; j++) xv[j] = *(const float4*)&x_lds[tq + 16 * j][k4 * 4];
                #pragma unroll
                for (int i = 0; i < 4; i++)
                    #pragma unroll
                    for (int j = 0; j < 4; j++) {
                        s[i][j].x += kv[i].x * xv[j].x;
                        s[i][j].y += kv[i].y * xv[j].y;
                        s[i][j].z += kv[i].z * xv[j].z;
                        s[i][j].w += kv[i].w * xv[j].w;
                    }
            }
            #pragma unroll
            for (int i = 0; i < 4; i++)
                #pragma unroll
                for (int j = 0; j < 4; j++) {
                    int d = td + 16 * i, bb = tq + 16 * j;
                    float dot = s[i][j].x + s[i][j].y + s[i][j].z + s[i][j].w;
                    float dist = (kn_lds[d] - 2.0f * dot + xn_lds[bb]) * (1.0f / SCALEF) + EPSF;
                    ker_lds[d][bb] = 1.0f / dist;
                }
        }
        __syncthreads();
        if (nvalid) {
            const float* vp = V + (size_t)d0 * NCOL + n4;
            for (int d = 0; d < dlim; d += 4) {
                float4 v0 = *(const float4*)(vp + (size_t)(d + 0) * NCOL);
                float4 v1 = *(const float4*)(vp + (size_t)(d + 1) * NCOL);
                float4 v2 = *(const float4*)(vp + (size_t)(d + 2) * NCOL);
                float4 v3 = *(const float4*)(vp + (size_t)(d + 3) * NCOL);
                #pragma unroll
                for (int j = 0; j < 16; j++) {
                    float k0 = ker_lds[d + 0][tb16 + j];
                    float k1 = ker_lds[d + 1][tb16 + j];
                    float k2 = ker_lds[d + 2][tb16 + j];
                    float k3 = ker_lds[d + 3][tb16 + j];
                    acc[j].x += k0 * v0.x + k1 * v1.x + k2 * v2.x + k3 * v3.x;
                    acc[j].y += k0 * v0.y + k1 * v1.y + k2 * v2.y + k3 * v3.y;
                    acc[j].z += k0 * v0.z + k1 * v1.z + k2 * v2.z + k3 * v3.z;
                    acc[j].w += k0 * v0.w + k1 * v1.w + k2 * v2.w + k3 * v3.w;
                }
            }
        }
    }
    if (nvalid) {
        #pragma unroll
        for (int j = 0; j < 16; j++) {
            int b = b0 + tb16 + j;
            *(float4*)(out + (size_t)b * NCOL + n4) = acc[j];
        }
    }
}

__global__ void normalize_kernel(float* __restrict__ out) {
    const int b = blockIdx.x;
    float* row = out + (size_t)b * NCOL;
    const int t = threadIdx.x;
    float s = 0.f;
    for (int n = t; n < NCOL; n += 256) s += row[n];
    __shared__ float red[4];
    #pragma unroll
    for (int off = 32; off > 0; off >>= 1) s += __shfl_down(s, off, 64);
    if ((t & 63) == 0) red[t >> 6] = s;
    __syncthreads();
    float inv = 1.0f / (red[0] + red[1] + red[2] + red[3]);
    for (int n = t; n < NCOL; n += 256) row[n] *= inv;
}

// ================= launch =================

extern "C" void kernel_launch(void* const* d_in, const int* in_sizes, int n_in,
                              void* d_out, int out_size, void* d_ws, size_t ws_size,
                              hipStream_t stream) {
    const float* x    = (const float*)d_in[0];
    const float* keys = (const float*)d_in[1];
    const float* V    = (const float*)d_in[2];
    float* out = (float*)d_out;

    // ws layout
    const size_t off_xn2 = 0;            // 4096 f32
    const size_t off_kn2 = 16384;        // 50048 f32
    const size_t off_xbf = 216576;       // 4096x64 bf16
    const size_t off_kbf = 740864;       // 50048x64 bf16
    const size_t off_vt  = 7147008;      // 1024x50048 bf16
    const size_t off_p   = 109645312;    // partial(s) f32
    const size_t PBYTES  = (size_t)B_ROWS * NCOL * 4;      // 16.384 MB
    const size_t total_atomic = off_p + PBYTES;            // ~126 MB
    const size_t total_parts  = off_p + DZ * PBYTES;       // ~175 MB

    if (ws_size >= total_atomic) {
        char* ws = (char*)d_ws;
        float* xn2 = (float*)(ws + off_xn2);
        float* kn2 = (float*)(ws + off_kn2);
        u16* x_bf  = (u16*)(ws + off_xbf);
        u16* k_bf  = (u16*)(ws + off_kbf);
        u16* vt    = (u16*)(ws + off_vt);
        float* partial = (float*)(ws + off_p);
        const int use_parts = (ws_size >= total_parts);

        prep_x_kernel<<<B_ROWS / 4, 256, 0, stream>>>(x, x_bf, xn2);
        prep_keys_kernel<<<DPAD / 4, 256, 0, stream>>>(keys, k_bf, kn2);
        prep_v_kernel<<<dim3(DPAD / 64, NPAD / 64), 256, 0, stream>>>(V, vt);
        if (!use_parts)
            zero_kernel<<<1024, 256, 0, stream>>>((float4*)partial,
                                                  (int)(PBYTES / 16));
        varkeys_mfma4_kernel<<<dim3(8, 16, DZ), 256, 0, stream>>>(
            x_bf, k_bf, vt, xn2, kn2, partial, use_parts ? 0 : 1);
        finish_kernel<<<B_ROWS, 256, 0, stream>>>(partial, out, use_parts ? DZ : 1);
    } else {
        float* xn = (float*)d_ws;
        float* kn = xn + B_ROWS;
        row_norm2_kernel<<<B_ROWS / 4, 256, 0, stream>>>(x, xn, B_ROWS);
        row_norm2_kernel<<<D_KEYS / 4 + 1, 256, 0, stream>>>(keys, kn, D_KEYS);
        dim3 grid(4, B_ROWS / BT);
        varkeys_main_kernel<<<grid, 256, 0, stream>>>(x, keys, V, xn, kn, out);
        normalize_kernel<<<B_ROWS, 256, 0, stream>>>(out);
    }
}

// Round 3
// 1057.607 us; speedup vs baseline: 1.1637x; 1.0466x over previous
//
#include <hip/hip_runtime.h>
#include <hip/hip_bf16.h>

typedef __attribute__((ext_vector_type(8))) short short8;
typedef __attribute__((ext_vector_type(16))) float f32x16;
typedef __attribute__((ext_vector_type(4))) unsigned int u32x4;
typedef __attribute__((ext_vector_type(2))) unsigned int u32x2;
typedef unsigned short u16;
typedef unsigned int u32;

#define B_ROWS 4096
#define D_KEYS 50000
#define DPAD   50048
#define KDIM   64
#define NCOL   1000
#define NPAD   1024
#define SCALEF 300000.0f
#define EPSF   1e-4f
#define NCHUNKS 782          // DPAD/64
#define NEG2S  (-2.0f / SCALEF)
#define DZ     2

// ---------------- helpers ----------------

__device__ __forceinline__ u16 f2bf(float f) {          // RNE float->bf16
    u32 u = __builtin_bit_cast(u32, f);
    u = (u + 0x7FFFu + ((u >> 16) & 1u)) >> 16;
    return (u16)u;
}

__device__ __forceinline__ u32 pack2(float a, float b) { // 2xf32 -> packed bf16x2
    __hip_bfloat162 r = __float22bfloat162_rn(make_float2(a, b));
    u32 pk;
    __builtin_memcpy(&pk, &r, 4);
    return pk;
}

__device__ __forceinline__ void glds16(const void* g, void* l) {
    __builtin_amdgcn_global_load_lds(
        (const __attribute__((address_space(1))) u32*)(uintptr_t)g,
        (__attribute__((address_space(3))) u32*)(uintptr_t)l, 16, 0, 0);
}

// ---------------- pre-pass kernels ----------------

__global__ void prep_x_kernel(const float* __restrict__ x,
                              u16* __restrict__ x_bf, float* __restrict__ xn2) {
    int row = (blockIdx.x * blockDim.x + threadIdx.x) >> 6;
    int lane = threadIdx.x & 63;
    if (row >= B_ROWS) return;
    float v = x[(size_t)row * KDIM + lane];
    x_bf[(size_t)row * KDIM + lane] = f2bf(v);
    float s = v * v;
    #pragma unroll
    for (int off = 32; off > 0; off >>= 1) s += __shfl_down(s, off, 64);
    if (lane == 0) xn2[row] = s * (1.0f / SCALEF);
}

__global__ void prep_keys_kernel(const float* __restrict__ keys,
                                 u16* __restrict__ keys_bf, float* __restrict__ kn2) {
    int row = (blockIdx.x * blockDim.x + threadIdx.x) >> 6;
    int lane = threadIdx.x & 63;
    if (row >= DPAD) return;
    float v = (row < D_KEYS) ? keys[(size_t)row * KDIM + lane] : 0.f;
    keys_bf[(size_t)row * KDIM + lane] = f2bf(v);
    float s = v * v;
    #pragma unroll
    for (int off = 32; off > 0; off >>= 1) s += __shfl_down(s, off, 64);
    if (lane == 0) kn2[row] = s * (1.0f / SCALEF) + EPSF;
}

// V (50000x1000 f32) -> vt fragment-major bf16:
// frag F = (d>>4)*32 + (n>>5); lane = (n&31) + 32*((d>>3)&1); u16 pos = F*512 + lane*8 + (d&7)
// A wave's PV B-operand (n-tile, k-chunk of 16 d) is then ONE coalesced 1KB load.
__global__ void prep_v_kernel(const float* __restrict__ V, u16* __restrict__ vt) {
    __shared__ float tile[64][65];
    const int d0 = blockIdx.x * 64;
    const int n0 = blockIdx.y * 64;
    const int t = threadIdx.x;
    #pragma unroll
    for (int p = 0; p < 16; p++) {
        int idx = p * 256 + t;
        int di = idx >> 6, nj = idx & 63;
        int d = d0 + di, n = n0 + nj;
        tile[di][nj] = (d < D_KEYS && n < NCOL) ? V[(size_t)d * NCOL + n] : 0.f;
    }
    __syncthreads();
    const int f = t >> 5;              // 8 fragments per 64x64 region
    const int sub = t & 31;
    const int Cl = f >> 1, ntl = f & 1;
    const size_t fragbase = ((size_t)((d0 >> 4) + Cl) * 32 + (size_t)(n0 >> 5) + ntl) * 512;
    #pragma unroll
    for (int lh = 0; lh < 2; lh++) {
        int L = sub + 32 * lh;         // lane position within fragment
        int nl = ntl * 32 + sub;       // n within the 64-tile
        int dbase = Cl * 16 + lh * 8;  // d within the 64-tile
        u32x4 pkv;
        pkv.x = pack2(tile[dbase + 0][nl], tile[dbase + 1][nl]);
        pkv.y = pack2(tile[dbase + 2][nl], tile[dbase + 3][nl]);
        pkv.z = pack2(tile[dbase + 4][nl], tile[dbase + 5][nl]);
        pkv.w = pack2(tile[dbase + 6][nl], tile[dbase + 7][nl]);
        *(u32x4*)&vt[fragbase + (size_t)L * 8] = pkv;
    }
}

__global__ void zero_kernel(float4* __restrict__ p, int n4) {
    for (int i = blockIdx.x * 256 + threadIdx.x; i < n4; i += gridDim.x * 256)
        p[i] = make_float4(0.f, 0.f, 0.f, 0.f);
}

// ---------------- main MFMA kernel ----------------
// grid (4 n-tiles, 64 b-tiles, DZ d-splits), 256 threads (4 waves)
// BM=64, BN=256, D-chunk 64. Cross-wave P sharing: each wave computes ONE
// 32x32 scores tile (dg=w>>1, bg=w&1), writes P to LDS (XOR-16B swizzle),
// all waves consume P as PV A-operand for their 64-col n-slice.
// V is NOT LDS-staged: PV B-fragments come as coalesced 1KB global loads
// from fragment-major vt (L2-resident per-chunk slice), issued early (T14).
// keys: single-buffered glds16 DMA issued after mid-barrier, drained at the
// end barrier with the whole PV phase hiding the latency.
__global__ __launch_bounds__(256, 2)
void varkeys_mfma5_kernel(const u16* __restrict__ x_bf,
                          const u16* __restrict__ keys_bf,
                          const u16* __restrict__ vt_bf,
                          const float* __restrict__ xn2,
                          const float* __restrict__ kn2,
                          float* __restrict__ partial,
                          int atomic_mode) {
    __shared__ alignas(16) u16 keys_lds[64 * 64];   // 8KB [d][k], 16B-swizzled
    __shared__ alignas(16) u16 p_lds[64 * 64];      // 8KB [b][d], 16B-swizzled

    const int t = threadIdx.x;
    const int w = t >> 6;
    const int lane = t & 63;
    const int half = lane >> 5;
    const int l31 = lane & 31;

    const int n0 = blockIdx.x * 256;
    const int b0 = blockIdx.y * 64;
    const int bz = blockIdx.z;
    const int c_begin = (bz * NCHUNKS) / DZ;
    const int c_end = ((bz + 1) * NCHUNKS) / DZ;

    // ---- scores-tile assignment: wave w -> (dg = w>>1, bg = w&1) ----
    const int dg = w >> 1;
    const int bg = w & 1;
    const int brow_s = b0 + bg * 32 + l31;         // scores output b-row
    const float xnv = xn2[brow_s];

    short8 xfrag[4];                               // scores B operand (x rows)
    #pragma unroll
    for (int kk = 0; kk < 4; kk++)
        xfrag[kk] = *(const short8*)(x_bf + (size_t)brow_s * KDIM + kk * 16 + half * 8);

    f32x16 acc[2][2];                              // [mg][nt] (64b x 64n per wave)
    #pragma unroll
    for (int mg = 0; mg < 2; mg++)
        #pragma unroll
        for (int nt = 0; nt < 2; nt++)
            #pragma unroll
            for (int i = 0; i < 16; i++) acc[mg][nt][i] = 0.f;

    // ---- precomputed LDS addresses (u16 units) ----
    const int dl = dg * 32 + l31;                  // scores A row (local d)
    int af_idx[4];
    #pragma unroll
    for (int kk = 0; kk < 4; kk++)
        af_idx[kk] = dl * 64 + (((kk * 2 + half) ^ (dl & 7)) * 8);

    int pr_idx[2][4];                              // PV A-operand reads
    #pragma unroll
    for (int mg = 0; mg < 2; mg++) {
        int pb = mg * 32 + l31;
        #pragma unroll
        for (int kk = 0; kk < 4; kk++)
            pr_idx[mg][kk] = pb * 64 + (((kk * 2 + half) ^ (pb & 7)) * 8);
    }

    const int bloc = bg * 32 + l31;                // P write row (local b)
    int pw_idx[4];
    #pragma unroll
    for (int m = 0; m < 4; m++)
        pw_idx[m] = bloc * 64 + (((dg * 4 + m) ^ (bloc & 7)) * 8) + half * 4;

    // vt fragment base for this wave (lane-resolved)
    const u16* vt_w = vt_bf + (size_t)((n0 >> 5) + w * 2) * 512 + (size_t)lane * 8;

    const int srow = lane >> 3;
    const int cg = (lane & 7) ^ srow;              // swizzled staging chunk

    auto stage_keys = [&](int c) {
        const int d0s = c * 64;
        #pragma unroll
        for (int q = 0; q < 2; q++) {
            int i = w * 2 + q;
            glds16(keys_bf + (size_t)(d0s + 8 * i + srow) * KDIM + cg * 8,
                   &keys_lds[i * 512]);
        }
    };

    stage_keys(c_begin);
    __syncthreads();                 // drain: keys buffer ready

    for (int c = c_begin; c < c_end; c++) {
        const int d0 = c * 64;
        const size_t cbase = (size_t)c * 65536;    // 4 C-chunks * 16384 u16

        // ---- issue early: V fragments kk=0,1 and kn (hidden under scores) ----
        short8 vfA[2][2];
        #pragma unroll
        for (int kk = 0; kk < 2; kk++)
            #pragma unroll
            for (int nt = 0; nt < 2; nt++)
                vfA[kk][nt] = *(const short8*)(vt_w + cbase + (size_t)kk * 16384 + nt * 512);
        float4 kn4[4];
        #pragma unroll
        for (int m = 0; m < 4; m++)
            kn4[m] = *(const float4*)(kn2 + d0 + dg * 32 + 8 * m + 4 * half);

        // ---- scores MFMA: one 32x32 tile per wave ----
        f32x16 s;
        #pragma unroll
        for (int i = 0; i < 16; i++) s[i] = 0.f;
        __builtin_amdgcn_s_setprio(1);
        #pragma unroll
        for (int kk = 0; kk < 4; kk++) {
            short8 af = *(const short8*)&keys_lds[af_idx[kk]];
            s = __builtin_amdgcn_mfma_f32_32x32x16_bf16(af, xfrag[kk], s, 0, 0, 0);
        }
        __builtin_amdgcn_s_setprio(0);

        // ---- epilogue: dist -> rcp -> bf16, write P to LDS ----
        const bool tail = (d0 + 64 > D_KEYS);
        const float* knf = reinterpret_cast<const float*>(kn4);
        #pragma unroll
        for (int m = 0; m < 4; m++) {
            float kv[4];
            #pragma unroll
            for (int j = 0; j < 4; j++) {
                int r = 4 * m + j;
                float dist = fmaf(s[r], NEG2S, knf[4 * m + j] + xnv);
                kv[j] = __builtin_amdgcn_rcpf(dist);
            }
            if (tail) {
                #pragma unroll
                for (int j = 0; j < 4; j++)
                    if (d0 + dg * 32 + 8 * m + 4 * half + j >= D_KEYS) kv[j] = 0.f;
            }
            u32x2 pw;
            pw.x = pack2(kv[0], kv[1]);
            pw.y = pack2(kv[2], kv[3]);
            *(u32x2*)&p_lds[pw_idx[m]] = pw;
        }

        __syncthreads();             // B: P visible to all waves

        // ---- issue: keys DMA for c+1 (drained at end barrier, hidden by PV) ----
        if (c + 1 < c_end) stage_keys(c + 1);
        // ---- issue: V fragments kk=2,3 (hidden under first half of PV) ----
        short8 vfB[2][2];
        #pragma unroll
        for (int kk = 0; kk < 2; kk++)
            #pragma unroll
            for (int nt = 0; nt < 2; nt++)
                vfB[kk][nt] = *(const short8*)(vt_w + cbase + (size_t)(kk + 2) * 16384 + nt * 512);

        // ---- PV MFMA: P (LDS) x V (regs) ----
        __builtin_amdgcn_s_setprio(1);
        #pragma unroll
        for (int kk = 0; kk < 4; kk++) {
            short8 pa0 = *(const short8*)&p_lds[pr_idx[0][kk]];
            short8 pa1 = *(const short8*)&p_lds[pr_idx[1][kk]];
            short8 vf0 = (kk < 2) ? vfA[kk][0] : vfB[kk - 2][0];
            short8 vf1 = (kk < 2) ? vfA[kk][1] : vfB[kk - 2][1];
            acc[0][0] = __builtin_amdgcn_mfma_f32_32x32x16_bf16(pa0, vf0, acc[0][0], 0, 0, 0);
            acc[1][0] = __builtin_amdgcn_mfma_f32_32x32x16_bf16(pa1, vf0, acc[1][0], 0, 0, 0);
            acc[0][1] = __builtin_amdgcn_mfma_f32_32x32x16_bf16(pa0, vf1, acc[0][1], 0, 0, 0);
            acc[1][1] = __builtin_amdgcn_mfma_f32_32x32x16_bf16(pa1, vf1, acc[1][1], 0, 0, 0);
        }
        __builtin_amdgcn_s_setprio(0);

        __syncthreads();             // A: keys(c+1) drained; P readers done
    }

    // ---- output: per-dz partial buffer, or atomicAdd ----
    float* pout = atomic_mode ? partial
                              : partial + (size_t)bz * B_ROWS * NCOL;
    #pragma unroll
    for (int mg = 0; mg < 2; mg++) {
        #pragma unroll
        for (int nt = 0; nt < 2; nt++) {
            int n = n0 + w * 64 + nt * 32 + l31;
            if (n < NCOL) {
                #pragma unroll
                for (int r = 0; r < 16; r++) {
                    int brow = b0 + mg * 32 + (r & 3) + 8 * (r >> 2) + 4 * half;
                    if (atomic_mode)
                        atomicAdd(&pout[(size_t)brow * NCOL + n], acc[mg][nt][r]);
                    else
                        pout[(size_t)brow * NCOL + n] = acc[mg][nt][r];
                }
            }
        }
    }
}

// sum pcount partials, row-normalize (values cached in regs across the 2 passes)
__global__ void finish_kernel(const float* __restrict__ partial, float* __restrict__ out,
                              int pcount) {
    const int b = blockIdx.x;
    const int t = threadIdx.x;
    float vv[4] = {0.f, 0.f, 0.f, 0.f};
    float s = 0.f;
    #pragma unroll
    for (int it = 0; it < 4; it++) {
        int n = t + it * 256;
        if (n < NCOL) {
            float v = 0.f;
            for (int p = 0; p < pcount; p++)
                v += partial[(size_t)p * B_ROWS * NCOL + (size_t)b * NCOL + n];
            vv[it] = v;
            s += v;
        }
    }
    __shared__ float red[4];
    #pragma unroll
    for (int off = 32; off > 0; off >>= 1) s += __shfl_down(s, off, 64);
    if ((t & 63) == 0) red[t >> 6] = s;
    __syncthreads();
    float inv = 1.0f / (red[0] + red[1] + red[2] + red[3]);
    #pragma unroll
    for (int it = 0; it < 4; it++) {
        int n = t + it * 256;
        if (n < NCOL) out[(size_t)b * NCOL + n] = vv[it] * inv;
    }
}

// ================= fallback fp32 path (round-1, known-correct) =================

__global__ void row_norm2_kernel(const float* __restrict__ a,
                                 float* __restrict__ out, int rows) {
    int wave = (blockIdx.x * blockDim.x + threadIdx.x) >> 6;
    int lane = threadIdx.x & 63;
    if (wave >= rows) return;
    float v = a[(size_t)wave * KDIM + lane];
    float s = v * v;
    #pragma unroll
    for (int off = 32; off > 0; off >>= 1) s += __shfl_down(s, off, 64);
    if (lane == 0) out[wave] = s;
}

#define DC 64
#define BT 64
#define NT 256

__global__ __launch_bounds__(256, 1)
void varkeys_main_kernel(const float* __restrict__ x,
                         const float* __restrict__ keys,
                         const float* __restrict__ V,
                         const float* __restrict__ xn,
                         const float* __restrict__ kn,
                         float* __restrict__ out) {
    __shared__ float x_lds[BT][68];
    __shared__ float keys_lds[DC][68];
    __shared__ float ker_lds[DC][65];
    __shared__ float xn_lds[BT];
    __shared__ float kn_lds[DC];
    const int t = threadIdx.x;
    const int n0 = blockIdx.x * NT;
    const int b0 = blockIdx.y * BT;
    for (int q = t; q < BT * 16; q += 256) {
        int row = q >> 4, c4 = q & 15;
        float4 v = *(const float4*)(x + (size_t)(b0 + row) * KDIM + c4 * 4);
        *(float4*)&x_lds[row][c4 * 4] = v;
    }
    if (t < BT) xn_lds[t] = xn[b0 + t];
    const int tn = t & 63;
    const int tb = t >> 6;
    const int tb16 = tb * 16;
    const int n4 = n0 + 4 * tn;
    const bool nvalid = (n4 < NCOL);
    float4 acc[16];
    #pragma unroll
    for (int j = 0; j < 16; j++) acc[j] = make_float4(0.f, 0.f, 0.f, 0.f);
    const int td = t & 15;
    const int tq = t >> 4;
    for (int d0 = 0; d0 < D_KEYS; d0 += DC) {
        const int dlim = min(DC, D_KEYS - d0);
        for (int q = t; q < DC * 16; q += 256) {
            int row = q >> 4, c4 = q & 15;
            if (d0 + row < D_KEYS) {
                float4 v = *(const float4*)(keys + (size_t)(d0 + row) * KDIM + c4 * 4);
                *(float4*)&keys_lds[row][c4 * 4] = v;
            }
        }
        if (t < DC) kn_lds[t] = (d0 + t < D_KEYS) ? kn[d0 + t] : 0.f;
        __syncthreads();
        {
            float4 s[4][4];
            #pragma unroll
            for (int i = 0; i < 4; i++)
                #pragma unroll
                for (int j = 0; j < 4; j++) s[i][j] = make_float4(0.f, 0.f, 0.f, 0.f);
            #pragma unroll
            for (int k4 = 0; k4 < 16; k4++) {
                float4 kv[4], xv[4];
                #pragma unroll
                for (int i = 0; i < 4; i++) kv[i] = *(const float4*)&keys_lds[td + 16 * i][k4 * 4];
                #pragma unroll
                for (int j = 0; j < 4; j++) xv[j] = *(const float4*)&x_lds[tq + 16 * j][k4 * 4];
                #pragma unroll
                for (int i = 0; i < 4; i++)
                    #pragma unroll
                    for (int j = 0; j < 4; j++) {
                        s[i][j].x += kv[i].x * xv[j].x;
                        s[i][j].y += kv[i].y * xv[j].y;
                        s[i][j].z += kv[i].z * xv[j].z;
                        s[i][j].w += kv[i].w * xv[j].w;
                    }
            }
            #pragma unroll
            for (int i = 0; i < 4; i++)
                #pragma unroll
                for (int j = 0; j < 4; j++) {
                    int d = td + 16 * i, bb = tq + 16 * j;
                    float dot = s[i][j].x + s[i][j].y + s[i][j].z + s[i][j].w;
                    float dist = (kn_lds[d] - 2.0f * dot + xn_lds[bb]) * (1.0f / SCALEF) + EPSF;
                    ker_lds[d][bb] = 1.0f / dist;
                }
        }
        __syncthreads();
        if (nvalid) {
            const float* vp = V + (size_t)d0 * NCOL + n4;
            for (int d = 0; d < dlim; d += 4) {
                float4 v0 = *(const float4*)(vp + (size_t)(d + 0) * NCOL);
                float4 v1 = *(const float4*)(vp + (size_t)(d + 1) * NCOL);
                float4 v2 = *(const float4*)(vp + (size_t)(d + 2) * NCOL);
                float4 v3 = *(const float4*)(vp + (size_t)(d + 3) * NCOL);
                #pragma unroll
                for (int j = 0; j < 16; j++) {
                    float k0 = ker_lds[d + 0][tb16 + j];
                    float k1 = ker_lds[d + 1][tb16 + j];
                    float k2 = ker_lds[d + 2][tb16 + j];
                    float k3 = ker_lds[d + 3][tb16 + j];
                    acc[j].x += k0 * v0.x + k1 * v1.x + k2 * v2.x + k3 * v3.x;
                    acc[j].y += k0 * v0.y + k1 * v1.y + k2 * v2.y + k3 * v3.y;
                    acc[j].z += k0 * v0.z + k1 * v1.z + k2 * v2.z + k3 * v3.z;
                    acc[j].w += k0 * v0.w + k1 * v1.w + k2 * v2.w + k3 * v3.w;
                }
            }
        }
    }
    if (nvalid) {
        #pragma unroll
        for (int j = 0; j < 16; j++) {
            int b = b0 + tb16 + j;
            *(float4*)(out + (size_t)b * NCOL + n4) = acc[j];
        }
    }
}

__global__ void normalize_kernel(float* __restrict__ out) {
    const int b = blockIdx.x;
    float* row = out + (size_t)b * NCOL;
    const int t = threadIdx.x;
    float s = 0.f;
    for (int n = t; n < NCOL; n += 256) s += row[n];
    __shared__ float red[4];
    #pragma unroll
    for (int off = 32; off > 0; off >>= 1) s += __shfl_down(s, off, 64);
    if ((t & 63) == 0) red[t >> 6] = s;
    __syncthreads();
    float inv = 1.0f / (red[0] + red[1] + red[2] + red[3]);
    for (int n = t; n < NCOL; n += 256) row[n] *= inv;
}

// ================= launch =================

extern "C" void kernel_launch(void* const* d_in, const int* in_sizes, int n_in,
                              void* d_out, int out_size, void* d_ws, size_t ws_size,
                              hipStream_t stream) {
    const float* x    = (const float*)d_in[0];
    const float* keys = (const float*)d_in[1];
    const float* V    = (const float*)d_in[2];
    float* out = (float*)d_out;

    // ws layout
    const size_t off_xn2 = 0;            // 4096 f32
    const size_t off_kn2 = 16384;        // 50048 f32
    const size_t off_xbf = 216576;       // 4096x64 bf16
    const size_t off_kbf = 740864;       // 50048x64 bf16
    const size_t off_vt  = 7147008;      // fragment-major bf16, 1024x50048 elems
    const size_t off_p   = 109645312;    // partial(s) f32
    const size_t PBYTES  = (size_t)B_ROWS * NCOL * 4;      // 16.384 MB
    const size_t total_atomic = off_p + PBYTES;            // ~126 MB
    const size_t total_parts  = off_p + DZ * PBYTES;       // ~142 MB

    if (ws_size >= total_atomic) {
        char* ws = (char*)d_ws;
        float* xn2 = (float*)(ws + off_xn2);
        float* kn2 = (float*)(ws + off_kn2);
        u16* x_bf  = (u16*)(ws + off_xbf);
        u16* k_bf  = (u16*)(ws + off_kbf);
        u16* vt    = (u16*)(ws + off_vt);
        float* partial = (float*)(ws + off_p);
        const int use_parts = (ws_size >= total_parts);

        prep_x_kernel<<<B_ROWS / 4, 256, 0, stream>>>(x, x_bf, xn2);
        prep_keys_kernel<<<DPAD / 4, 256, 0, stream>>>(keys, k_bf, kn2);
        prep_v_kernel<<<dim3(DPAD / 64, NPAD / 64), 256, 0, stream>>>(V, vt);
        if (!use_parts)
            zero_kernel<<<1024, 256, 0, stream>>>((float4*)partial,
                                                  (int)(PBYTES / 16));
        varkeys_mfma5_kernel<<<dim3(4, 64, DZ), 256, 0, stream>>>(
            x_bf, k_bf, vt, xn2, kn2, partial, use_parts ? 0 : 1);
        finish_kernel<<<B_ROWS, 256, 0, stream>>>(partial, out, use_parts ? DZ : 1);
    } else {
        float* xn = (float*)d_ws;
        float* kn = xn + B_ROWS;
        row_norm2_kernel<<<B_ROWS / 4, 256, 0, stream>>>(x, xn, B_ROWS);
        row_norm2_kernel<<<D_KEYS / 4 + 1, 256, 0, stream>>>(keys, kn, D_KEYS);
        dim3 grid(4, B_ROWS / BT);
        varkeys_main_kernel<<<grid, 256, 0, stream>>>(x, keys, V, xn, kn, out);
        normalize_kernel<<<B_ROWS, 256, 0, stream>>>(out);
    }
}

// Round 4
// 999.268 us; speedup vs baseline: 1.2316x; 1.0584x over previous
//
#include <hip/hip_runtime.h>
#include <hip/hip_bf16.h>

typedef __attribute__((ext_vector_type(8))) short short8;
typedef __attribute__((ext_vector_type(16))) float f32x16;
typedef __attribute__((ext_vector_type(4))) unsigned int u32x4;
typedef __attribute__((ext_vector_type(2))) unsigned int u32x2;
typedef unsigned short u16;
typedef unsigned int u32;

#define B_ROWS 4096
#define D_KEYS 50000
#define DPAD   50048
#define KDIM   64
#define NCOL   1000
#define NPAD   1024
#define SCALEF 300000.0f
#define EPSF   1e-4f
#define NCHUNKS 782          // DPAD/64
#define NEG2S  (-2.0f / SCALEF)
#define DZ     2

// ---------------- helpers ----------------

__device__ __forceinline__ u16 f2bf(float f) {          // RNE float->bf16
    u32 u = __builtin_bit_cast(u32, f);
    u = (u + 0x7FFFu + ((u >> 16) & 1u)) >> 16;
    return (u16)u;
}

__device__ __forceinline__ u32 pack2(float a, float b) { // 2xf32 -> packed bf16x2
    __hip_bfloat162 r = __float22bfloat162_rn(make_float2(a, b));
    u32 pk;
    __builtin_memcpy(&pk, &r, 4);
    return pk;
}

__device__ __forceinline__ void glds16(const void* g, void* l) {
    __builtin_amdgcn_global_load_lds(
        (const __attribute__((address_space(1))) u32*)(uintptr_t)g,
        (__attribute__((address_space(3))) u32*)(uintptr_t)l, 16, 0, 0);
}

// ---------------- pre-pass kernels ----------------

__global__ void prep_x_kernel(const float* __restrict__ x,
                              u16* __restrict__ x_bf, float* __restrict__ xn2) {
    int row = (blockIdx.x * blockDim.x + threadIdx.x) >> 6;
    int lane = threadIdx.x & 63;
    if (row >= B_ROWS) return;
    float v = x[(size_t)row * KDIM + lane];
    x_bf[(size_t)row * KDIM + lane] = f2bf(v);
    float s = v * v;
    #pragma unroll
    for (int off = 32; off > 0; off >>= 1) s += __shfl_down(s, off, 64);
    if (lane == 0) xn2[row] = s * (1.0f / SCALEF);
}

__global__ void prep_keys_kernel(const float* __restrict__ keys,
                                 u16* __restrict__ keys_bf, float* __restrict__ kn2) {
    int row = (blockIdx.x * blockDim.x + threadIdx.x) >> 6;
    int lane = threadIdx.x & 63;
    if (row >= DPAD) return;
    float v = (row < D_KEYS) ? keys[(size_t)row * KDIM + lane] : 0.f;
    keys_bf[(size_t)row * KDIM + lane] = f2bf(v);
    float s = v * v;
    #pragma unroll
    for (int off = 32; off > 0; off >>= 1) s += __shfl_down(s, off, 64);
    if (lane == 0) kn2[row] = s * (1.0f / SCALEF) + EPSF;
}

// V (50000x1000 f32) -> vt fragment-major bf16:
// frag F = (d>>4)*32 + (n>>5); lane = (n&31) + 32*((d>>3)&1); u16 pos = F*512 + lane*8 + (d&7)
// A wave's PV B-operand (n-tile, k-chunk of 16 d) is then ONE coalesced 1KB load.
__global__ void prep_v_kernel(const float* __restrict__ V, u16* __restrict__ vt) {
    __shared__ float tile[64][65];
    const int d0 = blockIdx.x * 64;
    const int n0 = blockIdx.y * 64;
    const int t = threadIdx.x;
    #pragma unroll
    for (int p = 0; p < 16; p++) {
        int idx = p * 256 + t;
        int di = idx >> 6, nj = idx & 63;
        int d = d0 + di, n = n0 + nj;
        tile[di][nj] = (d < D_KEYS && n < NCOL) ? V[(size_t)d * NCOL + n] : 0.f;
    }
    __syncthreads();
    const int f = t >> 5;              // 8 fragments per 64x64 region
    const int sub = t & 31;
    const int Cl = f >> 1, ntl = f & 1;
    const size_t fragbase = ((size_t)((d0 >> 4) + Cl) * 32 + (size_t)(n0 >> 5) + ntl) * 512;
    #pragma unroll
    for (int lh = 0; lh < 2; lh++) {
        int L = sub + 32 * lh;         // lane position within fragment
        int nl = ntl * 32 + sub;       // n within the 64-tile
        int dbase = Cl * 16 + lh * 8;  // d within the 64-tile
        u32x4 pkv;
        pkv.x = pack2(tile[dbase + 0][nl], tile[dbase + 1][nl]);
        pkv.y = pack2(tile[dbase + 2][nl], tile[dbase + 3][nl]);
        pkv.z = pack2(tile[dbase + 4][nl], tile[dbase + 5][nl]);
        pkv.w = pack2(tile[dbase + 6][nl], tile[dbase + 7][nl]);
        *(u32x4*)&vt[fragbase + (size_t)L * 8] = pkv;
    }
}

__global__ void zero_kernel(float4* __restrict__ p, int n4) {
    for (int i = blockIdx.x * 256 + threadIdx.x; i < n4; i += gridDim.x * 256)
        p[i] = make_float4(0.f, 0.f, 0.f, 0.f);
}

// ---------------- main MFMA kernel ----------------
// grid (4 n-tiles, 64 b-tiles, DZ d-splits), 256 threads (4 waves)
// BM=64, BN=256, D-chunk 64. Cross-wave P sharing as in mfma5, but with a
// depth-2 pipeline and ONE barrier per chunk:
//   - keys_lds and p_lds both double-buffered (32KB LDS total)
//   - at chunk top: issue keys DMA(c+1) -> alt buffer, V-fragments(c+1) -> vfn
//     regs, kn4(c). All drain at the single __syncthreads (cover = scores +
//     epilogue), PV then runs with zero memory waits.
//   - after PV: rotate vf <- vfn (32 v_movs).
// Race audit: keys WAR separated by barrier(c); P[buf] write(c)->barrier(c)->
// read(c); next write to same P buffer is epilogue(c+2) > barrier(c+1) > all
// PV(c) reads. scores(c+1) reads keys staged chunk c, drained at barrier(c).
__global__ __launch_bounds__(256, 2)
void varkeys_mfma6_kernel(const u16* __restrict__ x_bf,
                          const u16* __restrict__ keys_bf,
                          const u16* __restrict__ vt_bf,
                          const float* __restrict__ xn2,
                          const float* __restrict__ kn2,
                          float* __restrict__ partial,
                          int atomic_mode) {
    __shared__ alignas(16) u16 keys_lds[2][64 * 64];   // 2x8KB [d][k], 16B-swizzled
    __shared__ alignas(16) u16 p_lds[2][64 * 64];      // 2x8KB [b][d], 16B-swizzled

    const int t = threadIdx.x;
    const int w = t >> 6;
    const int lane = t & 63;
    const int half = lane >> 5;
    const int l31 = lane & 31;

    const int n0 = blockIdx.x * 256;
    const int b0 = blockIdx.y * 64;
    const int bz = blockIdx.z;
    const int c_begin = (bz * NCHUNKS) / DZ;
    const int c_end = ((bz + 1) * NCHUNKS) / DZ;

    // ---- scores-tile assignment: wave w -> (dg = w>>1, bg = w&1) ----
    const int dg = w >> 1;
    const int bg = w & 1;
    const int brow_s = b0 + bg * 32 + l31;         // scores output b-row
    const float xnv = xn2[brow_s];

    short8 xfrag[4];                               // scores B operand (x rows)
    #pragma unroll
    for (int kk = 0; kk < 4; kk++)
        xfrag[kk] = *(const short8*)(x_bf + (size_t)brow_s * KDIM + kk * 16 + half * 8);

    f32x16 acc[2][2];                              // [mg][nt] (64b x 64n per wave)
    #pragma unroll
    for (int mg = 0; mg < 2; mg++)
        #pragma unroll
        for (int nt = 0; nt < 2; nt++)
            #pragma unroll
            for (int i = 0; i < 16; i++) acc[mg][nt][i] = 0.f;

    // ---- precomputed LDS addresses (u16 units) ----
    const int dl = dg * 32 + l31;                  // scores A row (local d)
    int af_idx[4];
    #pragma unroll
    for (int kk = 0; kk < 4; kk++)
        af_idx[kk] = dl * 64 + (((kk * 2 + half) ^ (dl & 7)) * 8);

    int pr_idx[2][4];                              // PV A-operand reads
    #pragma unroll
    for (int mg = 0; mg < 2; mg++) {
        int pb = mg * 32 + l31;
        #pragma unroll
        for (int kk = 0; kk < 4; kk++)
            pr_idx[mg][kk] = pb * 64 + (((kk * 2 + half) ^ (pb & 7)) * 8);
    }

    const int bloc = bg * 32 + l31;                // P write row (local b)
    int pw_idx[4];
    #pragma unroll
    for (int m = 0; m < 4; m++)
        pw_idx[m] = bloc * 64 + (((dg * 4 + m) ^ (bloc & 7)) * 8) + half * 4;

    // vt fragment base for this wave (lane-resolved)
    const u16* vt_w = vt_bf + (size_t)((n0 >> 5) + w * 2) * 512 + (size_t)lane * 8;

    const int srow = lane >> 3;
    const int cg = (lane & 7) ^ srow;              // swizzled staging chunk

    auto stage_keys = [&](int c, int bi) {
        const int d0s = c * 64;
        #pragma unroll
        for (int q = 0; q < 2; q++) {
            int i = w * 2 + q;
            glds16(keys_bf + (size_t)(d0s + 8 * i + srow) * KDIM + cg * 8,
                   &keys_lds[bi][i * 512]);
        }
    };

    // ---- prologue: keys(c_begin) -> buf 0, V frags(c_begin) -> vf ----
    stage_keys(c_begin, 0);
    short8 vf[4][2];
    {
        const size_t cb0 = (size_t)c_begin * 65536;
        #pragma unroll
        for (int kk = 0; kk < 4; kk++)
            #pragma unroll
            for (int nt = 0; nt < 2; nt++)
                vf[kk][nt] = *(const short8*)(vt_w + cb0 + (size_t)kk * 16384 + nt * 512);
    }
    __syncthreads();                 // drain: keys buf0 + vf ready

    int buf = 0;
    for (int c = c_begin; c < c_end; c++) {
        const int d0 = c * 64;

        // ---- issue ALL next-chunk loads at chunk top (cover = scores+epilogue) ----
        if (c + 1 < c_end) stage_keys(c + 1, buf ^ 1);
        const int cn = (c + 1 < c_end) ? c + 1 : c;
        const size_t cbn = (size_t)cn * 65536;
        short8 vfn[4][2];
        #pragma unroll
        for (int kk = 0; kk < 4; kk++)
            #pragma unroll
            for (int nt = 0; nt < 2; nt++)
                vfn[kk][nt] = *(const short8*)(vt_w + cbn + (size_t)kk * 16384 + nt * 512);
        float4 kn4[4];
        #pragma unroll
        for (int m = 0; m < 4; m++)
            kn4[m] = *(const float4*)(kn2 + d0 + dg * 32 + 8 * m + 4 * half);

        // ---- scores MFMA: one 32x32 tile per wave ----
        const u16* klds = &keys_lds[buf][0];
        f32x16 s;
        #pragma unroll
        for (int i = 0; i < 16; i++) s[i] = 0.f;
        __builtin_amdgcn_s_setprio(1);
        #pragma unroll
        for (int kk = 0; kk < 4; kk++) {
            short8 af = *(const short8*)&klds[af_idx[kk]];
            s = __builtin_amdgcn_mfma_f32_32x32x16_bf16(af, xfrag[kk], s, 0, 0, 0);
        }
        __builtin_amdgcn_s_setprio(0);

        // ---- epilogue: dist -> rcp -> bf16, write P to p_lds[buf] ----
        const bool tail = (d0 + 64 > D_KEYS);
        const float* knf = reinterpret_cast<const float*>(kn4);
        u16* plw = &p_lds[buf][0];
        #pragma unroll
        for (int m = 0; m < 4; m++) {
            float kv[4];
            #pragma unroll
            for (int j = 0; j < 4; j++) {
                int r = 4 * m + j;
                float dist = fmaf(s[r], NEG2S, knf[4 * m + j] + xnv);
                kv[j] = __builtin_amdgcn_rcpf(dist);
            }
            if (tail) {
                #pragma unroll
                for (int j = 0; j < 4; j++)
                    if (d0 + dg * 32 + 8 * m + 4 * half + j >= D_KEYS) kv[j] = 0.f;
            }
            u32x2 pw;
            pw.x = pack2(kv[0], kv[1]);
            pw.y = pack2(kv[2], kv[3]);
            *(u32x2*)&plw[pw_idx[m]] = pw;
        }

        __syncthreads();             // single drain point: P visible, keys(c+1)
                                     // staged, vfn landed (scores+epilogue cover)

        // ---- PV MFMA: P (LDS) x V (regs) — zero memory waits ----
        const u16* plr = &p_lds[buf][0];
        __builtin_amdgcn_s_setprio(1);
        #pragma unroll
        for (int kk = 0; kk < 4; kk++) {
            short8 pa0 = *(const short8*)&plr[pr_idx[0][kk]];
            short8 pa1 = *(const short8*)&plr[pr_idx[1][kk]];
            acc[0][0] = __builtin_amdgcn_mfma_f32_32x32x16_bf16(pa0, vf[kk][0], acc[0][0], 0, 0, 0);
            acc[1][0] = __builtin_amdgcn_mfma_f32_32x32x16_bf16(pa1, vf[kk][0], acc[1][0], 0, 0, 0);
            acc[0][1] = __builtin_amdgcn_mfma_f32_32x32x16_bf16(pa0, vf[kk][1], acc[0][1], 0, 0, 0);
            acc[1][1] = __builtin_amdgcn_mfma_f32_32x32x16_bf16(pa1, vf[kk][1], acc[1][1], 0, 0, 0);
        }
        __builtin_amdgcn_s_setprio(0);

        // ---- rotate V regs for next chunk ----
        #pragma unroll
        for (int kk = 0; kk < 4; kk++)
            #pragma unroll
            for (int nt = 0; nt < 2; nt++)
                vf[kk][nt] = vfn[kk][nt];

        buf ^= 1;
    }

    // ---- output: per-dz partial buffer, or atomicAdd ----
    float* pout = atomic_mode ? partial
                              : partial + (size_t)bz * B_ROWS * NCOL;
    #pragma unroll
    for (int mg = 0; mg < 2; mg++) {
        #pragma unroll
        for (int nt = 0; nt < 2; nt++) {
            int n = n0 + w * 64 + nt * 32 + l31;
            if (n < NCOL) {
                #pragma unroll
                for (int r = 0; r < 16; r++) {
                    int brow = b0 + mg * 32 + (r & 3) + 8 * (r >> 2) + 4 * half;
                    if (atomic_mode)
                        atomicAdd(&pout[(size_t)brow * NCOL + n], acc[mg][nt][r]);
                    else
                        pout[(size_t)brow * NCOL + n] = acc[mg][nt][r];
                }
            }
        }
    }
}

// sum pcount partials, row-normalize (values cached in regs across the 2 passes)
__global__ void finish_kernel(const float* __restrict__ partial, float* __restrict__ out,
                              int pcount) {
    const int b = blockIdx.x;
    const int t = threadIdx.x;
    float vv[4] = {0.f, 0.f, 0.f, 0.f};
    float s = 0.f;
    #pragma unroll
    for (int it = 0; it < 4; it++) {
        int n = t + it * 256;
        if (n < NCOL) {
            float v = 0.f;
            for (int p = 0; p < pcount; p++)
                v += partial[(size_t)p * B_ROWS * NCOL + (size_t)b * NCOL + n];
            vv[it] = v;
            s += v;
        }
    }
    __shared__ float red[4];
    #pragma unroll
    for (int off = 32; off > 0; off >>= 1) s += __shfl_down(s, off, 64);
    if ((t & 63) == 0) red[t >> 6] = s;
    __syncthreads();
    float inv = 1.0f / (red[0] + red[1] + red[2] + red[3]);
    #pragma unroll
    for (int it = 0; it < 4; it++) {
        int n = t + it * 256;
        if (n < NCOL) out[(size_t)b * NCOL + n] = vv[it] * inv;
    }
}

// ================= fallback fp32 path (round-1, known-correct) =================

__global__ void row_norm2_kernel(const float* __restrict__ a,
                                 float* __restrict__ out, int rows) {
    int wave = (blockIdx.x * blockDim.x + threadIdx.x) >> 6;
    int lane = threadIdx.x & 63;
    if (wave >= rows) return;
    float v = a[(size_t)wave * KDIM + lane];
    float s = v * v;
    #pragma unroll
    for (int off = 32; off > 0; off >>= 1) s += __shfl_down(s, off, 64);
    if (lane == 0) out[wave] = s;
}

#define DC 64
#define BT 64
#define NT 256

__global__ __launch_bounds__(256, 1)
void varkeys_main_kernel(const float* __restrict__ x,
                         const float* __restrict__ keys,
                         const float* __restrict__ V,
                         const float* __restrict__ xn,
                         const float* __restrict__ kn,
                         float* __restrict__ out) {
    __shared__ float x_lds[BT][68];
    __shared__ float keys_lds[DC][68];
    __shared__ float ker_lds[DC][65];
    __shared__ float xn_lds[BT];
    __shared__ float kn_lds[DC];
    const int t = threadIdx.x;
    const int n0 = blockIdx.x * NT;
    const int b0 = blockIdx.y * BT;
    for (int q = t; q < BT * 16; q += 256) {
        int row = q >> 4, c4 = q & 15;
        float4 v = *(const float4*)(x + (size_t)(b0 + row) * KDIM + c4 * 4);
        *(float4*)&x_lds[row][c4 * 4] = v;
    }
    if (t < BT) xn_lds[t] = xn[b0 + t];
    const int tn = t & 63;
    const int tb = t >> 6;
    const int tb16 = tb * 16;
    const int n4 = n0 + 4 * tn;
    const bool nvalid = (n4 < NCOL);
    float4 acc[16];
    #pragma unroll
    for (int j = 0; j < 16; j++) acc[j] = make_float4(0.f, 0.f, 0.f, 0.f);
    const int td = t & 15;
    const int tq = t >> 4;
    for (int d0 = 0; d0 < D_KEYS; d0 += DC) {
        const int dlim = min(DC, D_KEYS - d0);
        for (int q = t; q < DC * 16; q += 256) {
            int row = q >> 4, c4 = q & 15;
            if (d0 + row < D_KEYS) {
                float4 v = *(const float4*)(keys + (size_t)(d0 + row) * KDIM + c4 * 4);
                *(float4*)&keys_lds[row][c4 * 4] = v;
            }
        }
        if (t < DC) kn_lds[t] = (d0 + t < D_KEYS) ? kn[d0 + t] : 0.f;
        __syncthreads();
        {
            float4 s[4][4];
            #pragma unroll
            for (int i = 0; i < 4; i++)
                #pragma unroll
                for (int j = 0; j < 4; j++) s[i][j] = make_float4(0.f, 0.f, 0.f, 0.f);
            #pragma unroll
            for (int k4 = 0; k4 < 16; k4++) {
                float4 kv[4], xv[4];
                #pragma unroll
                for (int i = 0; i < 4; i++) kv[i] = *(const float4*)&keys_lds[td + 16 * i][k4 * 4];
                #pragma unroll
                for (int j = 0; j < 4; j++) xv[j] = *(const float4*)&x_lds[tq + 16 * j][k4 * 4];
                #pragma unroll
                for (int i = 0; i < 4; i++)
                    #pragma unroll
                    for (int j = 0; j < 4; j++) {
                        s[i][j].x += kv[i].x * xv[j].x;
                        s[i][j].y += kv[i].y * xv[j].y;
                        s[i][j].z += kv[i].z * xv[j].z;
                        s[i][j].w += kv[i].w * xv[j].w;
                    }
            }
            #pragma unroll
            for (int i = 0; i < 4; i++)
                #pragma unroll
                for (int j = 0; j < 4; j++) {
                    int d = td + 16 * i, bb = tq + 16 * j;
                    float dot = s[i][j].x + s[i][j].y + s[i][j].z + s[i][j].w;
                    float dist = (kn_lds[d] - 2.0f * dot + xn_lds[bb]) * (1.0f / SCALEF) + EPSF;
                    ker_lds[d][bb] = 1.0f / dist;
                }
        }
        __syncthreads();
        if (nvalid) {
            const float* vp = V + (size_t)d0 * NCOL + n4;
            for (int d = 0; d < dlim; d += 4) {
                float4 v0 = *(const float4*)(vp + (size_t)(d + 0) * NCOL);
                float4 v1 = *(const float4*)(vp + (size_t)(d + 1) * NCOL);
                float4 v2 = *(const float4*)(vp + (size_t)(d + 2) * NCOL);
                float4 v3 = *(const float4*)(vp + (size_t)(d + 3) * NCOL);
                #pragma unroll
                for (int j = 0; j < 16; j++) {
                    float k0 = ker_lds[d + 0][tb16 + j];
                    float k1 = ker_lds[d + 1][tb16 + j];
                    float k2 = ker_lds[d + 2][tb16 + j];
                    float k3 = ker_lds[d + 3][tb16 + j];
                    acc[j].x += k0 * v0.x + k1 * v1.x + k2 * v2.x + k3 * v3.x;
                    acc[j].y += k0 * v0.y + k1 * v1.y + k2 * v2.y + k3 * v3.y;
                    acc[j].z += k0 * v0.z + k1 * v1.z + k2 * v2.z + k3 * v3.z;
                    acc[j].w += k0 * v0.w + k1 * v1.w + k2 * v2.w + k3 * v3.w;
                }
            }
        }
    }
    if (nvalid) {
        #pragma unroll
        for (int j = 0; j < 16; j++) {
            int b = b0 + tb16 + j;
            *(float4*)(out + (size_t)b * NCOL + n4) = acc[j];
        }
    }
}

__global__ void normalize_kernel(float* __restrict__ out) {
    const int b = blockIdx.x;
    float* row = out + (size_t)b * NCOL;
    const int t = threadIdx.x;
    float s = 0.f;
    for (int n = t; n < NCOL; n += 256) s += row[n];
    __shared__ float red[4];
    #pragma unroll
    for (int off = 32; off > 0; off >>= 1) s += __shfl_down(s, off, 64);
    if ((t & 63) == 0) red[t >> 6] = s;
    __syncthreads();
    float inv = 1.0f / (red[0] + red[1] + red[2] + red[3]);
    for (int n = t; n < NCOL; n += 256) row[n] *= inv;
}

// ================= launch =================

extern "C" void kernel_launch(void* const* d_in, const int* in_sizes, int n_in,
                              void* d_out, int out_size, void* d_ws, size_t ws_size,
                              hipStream_t stream) {
    const float* x    = (const float*)d_in[0];
    const float* keys = (const float*)d_in[1];
    const float* V    = (const float*)d_in[2];
    float* out = (float*)d_out;

    // ws layout
    const size_t off_xn2 = 0;            // 4096 f32
    const size_t off_kn2 = 16384;        // 50048 f32
    const size_t off_xbf = 216576;       // 4096x64 bf16
    const size_t off_kbf = 740864;       // 50048x64 bf16
    const size_t off_vt  = 7147008;      // fragment-major bf16, 1024x50048 elems
    const size_t off_p   = 109645312;    // partial(s) f32
    const size_t PBYTES  = (size_t)B_ROWS * NCOL * 4;      // 16.384 MB
    const size_t total_atomic = off_p + PBYTES;            // ~126 MB
    const size_t total_parts  = off_p + DZ * PBYTES;       // ~142 MB

    if (ws_size >= total_atomic) {
        char* ws = (char*)d_ws;
        float* xn2 = (float*)(ws + off_xn2);
        float* kn2 = (float*)(ws + off_kn2);
        u16* x_bf  = (u16*)(ws + off_xbf);
        u16* k_bf  = (u16*)(ws + off_kbf);
        u16* vt    = (u16*)(ws + off_vt);
        float* partial = (float*)(ws + off_p);
        const int use_parts = (ws_size >= total_parts);

        prep_x_kernel<<<B_ROWS / 4, 256, 0, stream>>>(x, x_bf, xn2);
        prep_keys_kernel<<<DPAD / 4, 256, 0, stream>>>(keys, k_bf, kn2);
        prep_v_kernel<<<dim3(DPAD / 64, NPAD / 64), 256, 0, stream>>>(V, vt);
        if (!use_parts)
            zero_kernel<<<1024, 256, 0, stream>>>((float4*)partial,
                                                  (int)(PBYTES / 16));
        varkeys_mfma6_kernel<<<dim3(4, 64, DZ), 256, 0, stream>>>(
            x_bf, k_bf, vt, xn2, kn2, partial, use_parts ? 0 : 1);
        finish_kernel<<<B_ROWS, 256, 0, stream>>>(partial, out, use_parts ? DZ : 1);
    } else {
        float* xn = (float*)d_ws;
        float* kn = xn + B_ROWS;
        row_norm2_kernel<<<B_ROWS / 4, 256, 0, stream>>>(x, xn, B_ROWS);
        row_norm2_kernel<<<D_KEYS / 4 + 1, 256, 0, stream>>>(keys, kn, D_KEYS);
        dim3 grid(4, B_ROWS / BT);
        varkeys_main_kernel<<<grid, 256, 0, stream>>>(x, keys, V, xn, kn, out);
        normalize_kernel<<<B_ROWS, 256, 0, stream>>>(out);
    }
}

// Round 5
// 980.530 us; speedup vs baseline: 1.2552x; 1.0191x over previous
//
#include <hip/hip_runtime.h>
#include <hip/hip_bf16.h>

typedef __attribute__((ext_vector_type(8))) short short8;
typedef __attribute__((ext_vector_type(16))) float f32x16;
typedef __attribute__((ext_vector_type(4))) unsigned int u32x4;
typedef __attribute__((ext_vector_type(2))) unsigned int u32x2;
typedef unsigned short u16;
typedef unsigned int u32;

#define B_ROWS 4096
#define D_KEYS 50000
#define DPAD   50048
#define KDIM   64
#define NCOL   1000
#define NPAD   1024
#define SCALEF 300000.0f
#define EPSF   1e-4f
#define NCHUNKS 782          // DPAD/64
#define NEG2S  (-2.0f / SCALEF)
#define DZ     2

// raw block barrier: LDS-visibility only (lgkmcnt), NO vmcnt drain.
// Legal because the only cross-wave memory in the main loop is p_lds
// (ds_write -> lgkmcnt(0) -> s_barrier). Register VMEM prefetches stay
// in flight across the barrier; compiler inserts counted vmcnt at use.
#define BLOCK_SYNC() do {                                   \
    asm volatile("s_waitcnt lgkmcnt(0)" ::: "memory");      \
    __builtin_amdgcn_s_barrier();                           \
    __builtin_amdgcn_sched_barrier(0);                      \
} while (0)

// ---------------- helpers ----------------

__device__ __forceinline__ u16 f2bf(float f) {          // RNE float->bf16
    u32 u = __builtin_bit_cast(u32, f);
    u = (u + 0x7FFFu + ((u >> 16) & 1u)) >> 16;
    return (u16)u;
}

__device__ __forceinline__ u32 pack2(float a, float b) { // 2xf32 -> packed bf16x2
    __hip_bfloat162 r = __float22bfloat162_rn(make_float2(a, b));
    u32 pk;
    __builtin_memcpy(&pk, &r, 4);
    return pk;
}

// ---------------- pre-pass kernels ----------------

__global__ void prep_x_kernel(const float* __restrict__ x,
                              u16* __restrict__ x_bf, float* __restrict__ xn2) {
    int row = (blockIdx.x * blockDim.x + threadIdx.x) >> 6;
    int lane = threadIdx.x & 63;
    if (row >= B_ROWS) return;
    float v = x[(size_t)row * KDIM + lane];
    x_bf[(size_t)row * KDIM + lane] = f2bf(v);
    float s = v * v;
    #pragma unroll
    for (int off = 32; off > 0; off >>= 1) s += __shfl_down(s, off, 64);
    if (lane == 0) xn2[row] = s * (1.0f / SCALEF);
}

__global__ void prep_keys_kernel(const float* __restrict__ keys,
                                 u16* __restrict__ keys_bf, float* __restrict__ kn2) {
    int row = (blockIdx.x * blockDim.x + threadIdx.x) >> 6;
    int lane = threadIdx.x & 63;
    if (row >= DPAD) return;
    float v = (row < D_KEYS) ? keys[(size_t)row * KDIM + lane] : 0.f;
    keys_bf[(size_t)row * KDIM + lane] = f2bf(v);
    float s = v * v;
    #pragma unroll
    for (int off = 32; off > 0; off >>= 1) s += __shfl_down(s, off, 64);
    if (lane == 0) kn2[row] = s * (1.0f / SCALEF) + EPSF;
}

// keys_bf (row-major, zero-padded) -> kt fragment-major MFMA-A fragments:
// frag F = c*8 + dg*4 + kk  (c: 64-row chunk, dg: 32-row half, kk: 16-col k-step)
// lane L holds keys[(c*64 + dg*32 + (L&31))][kk*16 + (L>>5)*8 + j], j=0..7.
// Main-kernel af[kk] load = ONE coalesced 1KB global_load_dwordx4 per frag.
__global__ void prep_kt_kernel(const u16* __restrict__ keys_bf, u16* __restrict__ kt) {
    const int c = blockIdx.x;
    const int t = threadIdx.x;
    const int w = t >> 6;
    const int L = t & 63;
    const int dg = w >> 1;
    #pragma unroll
    for (int q = 0; q < 2; q++) {
        int kk = (w & 1) * 2 + q;
        int row = c * 64 + dg * 32 + (L & 31);
        int col = kk * 16 + (L >> 5) * 8;
        u32x4 v = *(const u32x4*)&keys_bf[(size_t)row * KDIM + col];
        size_t F = (size_t)c * 8 + dg * 4 + kk;
        *(u32x4*)&kt[F * 512 + (size_t)L * 8] = v;
    }
}

// V (50000x1000 f32) -> vt fragment-major bf16:
// frag F = (d>>4)*32 + (n>>5); lane = (n&31) + 32*((d>>3)&1); u16 pos = F*512 + lane*8 + (d&7)
__global__ void prep_v_kernel(const float* __restrict__ V, u16* __restrict__ vt) {
    __shared__ float tile[64][65];
    const int d0 = blockIdx.x * 64;
    const int n0 = blockIdx.y * 64;
    const int t = threadIdx.x;
    #pragma unroll
    for (int p = 0; p < 16; p++) {
        int idx = p * 256 + t;
        int di = idx >> 6, nj = idx & 63;
        int d = d0 + di, n = n0 + nj;
        tile[di][nj] = (d < D_KEYS && n < NCOL) ? V[(size_t)d * NCOL + n] : 0.f;
    }
    __syncthreads();
    const int f = t >> 5;              // 8 fragments per 64x64 region
    const int sub = t & 31;
    const int Cl = f >> 1, ntl = f & 1;
    const size_t fragbase = ((size_t)((d0 >> 4) + Cl) * 32 + (size_t)(n0 >> 5) + ntl) * 512;
    #pragma unroll
    for (int lh = 0; lh < 2; lh++) {
        int L = sub + 32 * lh;         // lane position within fragment
        int nl = ntl * 32 + sub;       // n within the 64-tile
        int dbase = Cl * 16 + lh * 8;  // d within the 64-tile
        u32x4 pkv;
        pkv.x = pack2(tile[dbase + 0][nl], tile[dbase + 1][nl]);
        pkv.y = pack2(tile[dbase + 2][nl], tile[dbase + 3][nl]);
        pkv.z = pack2(tile[dbase + 4][nl], tile[dbase + 5][nl]);
        pkv.w = pack2(tile[dbase + 6][nl], tile[dbase + 7][nl]);
        *(u32x4*)&vt[fragbase + (size_t)L * 8] = pkv;
    }
}

__global__ void zero_kernel(float4* __restrict__ p, int n4) {
    for (int i = blockIdx.x * 256 + threadIdx.x; i < n4; i += gridDim.x * 256)
        p[i] = make_float4(0.f, 0.f, 0.f, 0.f);
}

// ---------------- main MFMA kernel ----------------
// grid (4 n-tiles, 64 b-tiles, DZ d-splits), 256 threads (4 waves)
// BM=64, BN=256, D-chunk 64. Cross-wave P sharing; ALL operands except P
// arrive as registers (keys + V fragment-major global loads, L2/L3-hot).
// p_lds double-buffered, ONE raw barrier per chunk (lgkmcnt-only drain) ->
// register prefetches issued at top of chunk c are consumed in chunk c+1
// with a FULL chunk (~1900 cyc) of cover; no vmcnt(0) drain anywhere.
// Issue order at chunk top: kn4 FIRST, then afn, then vfn (FIFO vmcnt:
// waiting on kn4 must not force later loads to complete).
__global__ __launch_bounds__(256, 2)
void varkeys_mfma7_kernel(const u16* __restrict__ kt,
                          const u16* __restrict__ x_bf,
                          const u16* __restrict__ vt_bf,
                          const float* __restrict__ xn2,
                          const float* __restrict__ kn2,
                          float* __restrict__ partial,
                          int atomic_mode) {
    __shared__ alignas(16) u16 p_lds[2][64 * 64];      // 2x8KB [b][d], 16B-swizzled

    const int t = threadIdx.x;
    const int w = t >> 6;
    const int lane = t & 63;
    const int half = lane >> 5;
    const int l31 = lane & 31;

    const int n0 = blockIdx.x * 256;
    const int b0 = blockIdx.y * 64;
    const int bz = blockIdx.z;
    const int c_begin = (bz * NCHUNKS) / DZ;
    const int c_end = ((bz + 1) * NCHUNKS) / DZ;

    // ---- scores-tile assignment: wave w -> (dg = w>>1, bg = w&1) ----
    const int dg = w >> 1;
    const int bg = w & 1;
    const int brow_s = b0 + bg * 32 + l31;         // scores output b-row
    const float xnv = xn2[brow_s];

    short8 xfrag[4];                               // scores B operand (x rows)
    #pragma unroll
    for (int kk = 0; kk < 4; kk++)
        xfrag[kk] = *(const short8*)(x_bf + (size_t)brow_s * KDIM + kk * 16 + half * 8);

    f32x16 acc[2][2];                              // [mg][nt] (64b x 64n per wave)
    #pragma unroll
    for (int mg = 0; mg < 2; mg++)
        #pragma unroll
        for (int nt = 0; nt < 2; nt++)
            #pragma unroll
            for (int i = 0; i < 16; i++) acc[mg][nt][i] = 0.f;

    // ---- precomputed LDS addresses (u16 units) ----
    int pr_idx[2][4];                              // PV A-operand reads
    #pragma unroll
    for (int mg = 0; mg < 2; mg++) {
        int pb = mg * 32 + l31;
        #pragma unroll
        for (int kk = 0; kk < 4; kk++)
            pr_idx[mg][kk] = pb * 64 + (((kk * 2 + half) ^ (pb & 7)) * 8);
    }

    const int bloc = bg * 32 + l31;                // P write row (local b)
    int pw_idx[4];
    #pragma unroll
    for (int m = 0; m < 4; m++)
        pw_idx[m] = bloc * 64 + (((dg * 4 + m) ^ (bloc & 7)) * 8) + half * 4;

    // global fragment bases (lane-resolved)
    const u16* kt_w = kt + (size_t)(dg * 4) * 512 + (size_t)lane * 8;
    const u16* vt_w = vt_bf + (size_t)((n0 >> 5) + w * 2) * 512 + (size_t)lane * 8;

    // ---- prologue: af/vf for c_begin (exposed latency once) ----
    short8 af[4], vf[4][2];
    {
        const size_t ck = (size_t)c_begin * 4096;      // 8 frags * 512
        const size_t cv = (size_t)c_begin * 65536;     // 128 frags * 512
        #pragma unroll
        for (int kk = 0; kk < 4; kk++)
            af[kk] = *(const short8*)(kt_w + ck + (size_t)kk * 512);
        #pragma unroll
        for (int kk = 0; kk < 4; kk++)
            #pragma unroll
            for (int nt = 0; nt < 2; nt++)
                vf[kk][nt] = *(const short8*)(vt_w + cv + (size_t)kk * 16384 + nt * 512);
    }

    int buf = 0;
    for (int c = c_begin; c < c_end; c++) {
        const int d0 = c * 64;

        // ---- issue next-chunk prefetches: kn FIRST, then afn, then vfn ----
        float4 kn4[4];
        #pragma unroll
        for (int m = 0; m < 4; m++)
            kn4[m] = *(const float4*)(kn2 + d0 + dg * 32 + 8 * m + 4 * half);

        const int cn = (c + 1 < c_end) ? c + 1 : c;
        const size_t ckn = (size_t)cn * 4096;
        const size_t cvn = (size_t)cn * 65536;
        short8 afn[4];
        #pragma unroll
        for (int kk = 0; kk < 4; kk++)
            afn[kk] = *(const short8*)(kt_w + ckn + (size_t)kk * 512);
        short8 vfn[4][2];
        #pragma unroll
        for (int kk = 0; kk < 4; kk++)
            #pragma unroll
            for (int nt = 0; nt < 2; nt++)
                vfn[kk][nt] = *(const short8*)(vt_w + cvn + (size_t)kk * 16384 + nt * 512);

        // ---- scores MFMA: one 32x32 tile per wave, all-register operands ----
        f32x16 s;
        #pragma unroll
        for (int i = 0; i < 16; i++) s[i] = 0.f;
        __builtin_amdgcn_s_setprio(1);
        #pragma unroll
        for (int kk = 0; kk < 4; kk++)
            s = __builtin_amdgcn_mfma_f32_32x32x16_bf16(af[kk], xfrag[kk], s, 0, 0, 0);
        __builtin_amdgcn_s_setprio(0);

        // ---- epilogue: dist -> rcp -> bf16, write P to p_lds[buf] ----
        const bool tail = (d0 + 64 > D_KEYS);
        const float* knf = reinterpret_cast<const float*>(kn4);
        u16* plw = &p_lds[buf][0];
        #pragma unroll
        for (int m = 0; m < 4; m++) {
            float kv[4];
            #pragma unroll
            for (int j = 0; j < 4; j++) {
                int r = 4 * m + j;
                float dist = fmaf(s[r], NEG2S, knf[4 * m + j] + xnv);
                kv[j] = __builtin_amdgcn_rcpf(dist);
            }
            if (tail) {
                #pragma unroll
                for (int j = 0; j < 4; j++)
                    if (d0 + dg * 32 + 8 * m + 4 * half + j >= D_KEYS) kv[j] = 0.f;
            }
            u32x2 pw;
            pw.x = pack2(kv[0], kv[1]);
            pw.y = pack2(kv[2], kv[3]);
            *(u32x2*)&plw[pw_idx[m]] = pw;
        }

        BLOCK_SYNC();                // lgkmcnt(0) + s_barrier: P visible.
                                     // Register prefetches stay in flight.

        // ---- PV MFMA: P (LDS) x V (regs) ----
        const u16* plr = &p_lds[buf][0];
        __builtin_amdgcn_s_setprio(1);
        #pragma unroll
        for (int kk = 0; kk < 4; kk++) {
            short8 pa0 = *(const short8*)&plr[pr_idx[0][kk]];
            short8 pa1 = *(const short8*)&plr[pr_idx[1][kk]];
            acc[0][0] = __builtin_amdgcn_mfma_f32_32x32x16_bf16(pa0, vf[kk][0], acc[0][0], 0, 0, 0);
            acc[1][0] = __builtin_amdgcn_mfma_f32_32x32x16_bf16(pa1, vf[kk][0], acc[1][0], 0, 0, 0);
            acc[0][1] = __builtin_amdgcn_mfma_f32_32x32x16_bf16(pa0, vf[kk][1], acc[0][1], 0, 0, 0);
            acc[1][1] = __builtin_amdgcn_mfma_f32_32x32x16_bf16(pa1, vf[kk][1], acc[1][1], 0, 0, 0);
        }
        __builtin_amdgcn_s_setprio(0);

        // ---- rotate prefetched regs ----
        #pragma unroll
        for (int kk = 0; kk < 4; kk++) af[kk] = afn[kk];
        #pragma unroll
        for (int kk = 0; kk < 4; kk++)
            #pragma unroll
            for (int nt = 0; nt < 2; nt++) vf[kk][nt] = vfn[kk][nt];

        buf ^= 1;
    }

    // ---- output: per-dz partial buffer, or atomicAdd ----
    float* pout = atomic_mode ? partial
                              : partial + (size_t)bz * B_ROWS * NCOL;
    #pragma unroll
    for (int mg = 0; mg < 2; mg++) {
        #pragma unroll
        for (int nt = 0; nt < 2; nt++) {
            int n = n0 + w * 64 + nt * 32 + l31;
            if (n < NCOL) {
                #pragma unroll
                for (int r = 0; r < 16; r++) {
                    int brow = b0 + mg * 32 + (r & 3) + 8 * (r >> 2) + 4 * half;
                    if (atomic_mode)
                        atomicAdd(&pout[(size_t)brow * NCOL + n], acc[mg][nt][r]);
                    else
                        pout[(size_t)brow * NCOL + n] = acc[mg][nt][r];
                }
            }
        }
    }
}

// sum pcount partials, row-normalize (values cached in regs across the 2 passes)
__global__ void finish_kernel(const float* __restrict__ partial, float* __restrict__ out,
                              int pcount) {
    const int b = blockIdx.x;
    const int t = threadIdx.x;
    float vv[4] = {0.f, 0.f, 0.f, 0.f};
    float s = 0.f;
    #pragma unroll
    for (int it = 0; it < 4; it++) {
        int n = t + it * 256;
        if (n < NCOL) {
            float v = 0.f;
            for (int p = 0; p < pcount; p++)
                v += partial[(size_t)p * B_ROWS * NCOL + (size_t)b * NCOL + n];
            vv[it] = v;
            s += v;
        }
    }
    __shared__ float red[4];
    #pragma unroll
    for (int off = 32; off > 0; off >>= 1) s += __shfl_down(s, off, 64);
    if ((t & 63) == 0) red[t >> 6] = s;
    __syncthreads();
    float inv = 1.0f / (red[0] + red[1] + red[2] + red[3]);
    #pragma unroll
    for (int it = 0; it < 4; it++) {
        int n = t + it * 256;
        if (n < NCOL) out[(size_t)b * NCOL + n] = vv[it] * inv;
    }
}

// ================= fallback fp32 path (round-1, known-correct) =================

__global__ void row_norm2_kernel(const float* __restrict__ a,
                                 float* __restrict__ out, int rows) {
    int wave = (blockIdx.x * blockDim.x + threadIdx.x) >> 6;
    int lane = threadIdx.x & 63;
    if (wave >= rows) return;
    float v = a[(size_t)wave * KDIM + lane];
    float s = v * v;
    #pragma unroll
    for (int off = 32; off > 0; off >>= 1) s += __shfl_down(s, off, 64);
    if (lane == 0) out[wave] = s;
}

#define DC 64
#define BT 64
#define NT 256

__global__ __launch_bounds__(256, 1)
void varkeys_main_kernel(const float* __restrict__ x,
                         const float* __restrict__ keys,
                         const float* __restrict__ V,
                         const float* __restrict__ xn,
                         const float* __restrict__ kn,
                         float* __restrict__ out) {
    __shared__ float x_lds[BT][68];
    __shared__ float keys_lds[DC][68];
    __shared__ float ker_lds[DC][65];
    __shared__ float xn_lds[BT];
    __shared__ float kn_lds[DC];
    const int t = threadIdx.x;
    const int n0 = blockIdx.x * NT;
    const int b0 = blockIdx.y * BT;
    for (int q = t; q < BT * 16; q += 256) {
        int row = q >> 4, c4 = q & 15;
        float4 v = *(const float4*)(x + (size_t)(b0 + row) * KDIM + c4 * 4);
        *(float4*)&x_lds[row][c4 * 4] = v;
    }
    if (t < BT) xn_lds[t] = xn[b0 + t];
    const int tn = t & 63;
    const int tb = t >> 6;
    const int tb16 = tb * 16;
    const int n4 = n0 + 4 * tn;
    const bool nvalid = (n4 < NCOL);
    float4 acc[16];
    #pragma unroll
    for (int j = 0; j < 16; j++) acc[j] = make_float4(0.f, 0.f, 0.f, 0.f);
    const int td = t & 15;
    const int tq = t >> 4;
    for (int d0 = 0; d0 < D_KEYS; d0 += DC) {
        const int dlim = min(DC, D_KEYS - d0);
        for (int q = t; q < DC * 16; q += 256) {
            int row = q >> 4, c4 = q & 15;
            if (d0 + row < D_KEYS) {
                float4 v = *(const float4*)(keys + (size_t)(d0 + row) * KDIM + c4 * 4);
                *(float4*)&keys_lds[row][c4 * 4] = v;
            }
        }
        if (t < DC) kn_lds[t] = (d0 + t < D_KEYS) ? kn[d0 + t] : 0.f;
        __syncthreads();
        {
            float4 s[4][4];
            #pragma unroll
            for (int i = 0; i < 4; i++)
                #pragma unroll
                for (int j = 0; j < 4; j++) s[i][j] = make_float4(0.f, 0.f, 0.f, 0.f);
            #pragma unroll
            for (int k4 = 0; k4 < 16; k4++) {
                float4 kv[4], xv[4];
                #pragma unroll
                for (int i = 0; i < 4; i++) kv[i] = *(const float4*)&keys_lds[td + 16 * i][k4 * 4];
                #pragma unroll
                for (int j = 0; j < 4; j++) xv[j] = *(const float4*)&x_lds[tq + 16 * j][k4 * 4];
                #pragma unroll
                for (int i = 0; i < 4; i++)
                    #pragma unroll
                    for (int j = 0; j < 4; j++) {
                        s[i][j].x += kv[i].x * xv[j].x;
                        s[i][j].y += kv[i].y * xv[j].y;
                        s[i][j].z += kv[i].z * xv[j].z;
                        s[i][j].w += kv[i].w * xv[j].w;
                    }
            }
            #pragma unroll
            for (int i = 0; i < 4; i++)
                #pragma unroll
                for (int j = 0; j < 4; j++) {
                    int d = td + 16 * i, bb = tq + 16 * j;
                    float dot = s[i][j].x + s[i][j].y + s[i][j].z + s[i][j].w;
                    float dist = (kn_lds[d] - 2.0f * dot + xn_lds[bb]) * (1.0f / SCALEF) + EPSF;
                    ker_lds[d][bb] = 1.0f / dist;
                }
        }
        __syncthreads();
        if (nvalid) {
            const float* vp = V + (size_t)d0 * NCOL + n4;
            for (int d = 0; d < dlim; d += 4) {
                float4 v0 = *(const float4*)(vp + (size_t)(d + 0) * NCOL);
                float4 v1 = *(const float4*)(vp + (size_t)(d + 1) * NCOL);
                float4 v2 = *(const float4*)(vp + (size_t)(d + 2) * NCOL);
                float4 v3 = *(const float4*)(vp + (size_t)(d + 3) * NCOL);
                #pragma unroll
                for (int j = 0; j < 16; j++) {
                    float k0 = ker_lds[d + 0][tb16 + j];
                    float k1 = ker_lds[d + 1][tb16 + j];
                    float k2 = ker_lds[d + 2][tb16 + j];
                    float k3 = ker_lds[d + 3][tb16 + j];
                    acc[j].x += k0 * v0.x + k1 * v1.x + k2 * v2.x + k3 * v3.x;
                    acc[j].y += k0 * v0.y + k1 * v1.y + k2 * v2.y + k3 * v3.y;
                    acc[j].z += k0 * v0.z + k1 * v1.z + k2 * v2.z + k3 * v3.z;
                    acc[j].w += k0 * v0.w + k1 * v1.w + k2 * v2.w + k3 * v3.w;
                }
            }
        }
    }
    if (nvalid) {
        #pragma unroll
        for (int j = 0; j < 16; j++) {
            int b = b0 + tb16 + j;
            *(float4*)(out + (size_t)b * NCOL + n4) = acc[j];
        }
    }
}

__global__ void normalize_kernel(float* __restrict__ out) {
    const int b = blockIdx.x;
    float* row = out + (size_t)b * NCOL;
    const int t = threadIdx.x;
    float s = 0.f;
    for (int n = t; n < NCOL; n += 256) s += row[n];
    __shared__ float red[4];
    #pragma unroll
    for (int off = 32; off > 0; off >>= 1) s += __shfl_down(s, off, 64);
    if ((t & 63) == 0) red[t >> 6] = s;
    __syncthreads();
    float inv = 1.0f / (red[0] + red[1] + red[2] + red[3]);
    for (int n = t; n < NCOL; n += 256) row[n] *= inv;
}

// ================= launch =================

extern "C" void kernel_launch(void* const* d_in, const int* in_sizes, int n_in,
                              void* d_out, int out_size, void* d_ws, size_t ws_size,
                              hipStream_t stream) {
    const float* x    = (const float*)d_in[0];
    const float* keys = (const float*)d_in[1];
    const float* V    = (const float*)d_in[2];
    float* out = (float*)d_out;

    // ws layout
    const size_t off_xn2 = 0;            // 4096 f32
    const size_t off_kn2 = 16384;        // 50048 f32
    const size_t off_xbf = 216576;       // 4096x64 bf16
    const size_t off_kbf = 740864;       // 50048x64 bf16 (row-major, prep_kt src)
    const size_t off_vt  = 7147008;      // fragment-major V bf16 (102.5 MB)
    const size_t off_kt  = 109645312;    // fragment-major keys bf16 (6.4 MB)
    const size_t off_p   = 116051456;    // partial(s) f32
    const size_t PBYTES  = (size_t)B_ROWS * NCOL * 4;      // 16.384 MB
    const size_t total_atomic = off_p + PBYTES;            // ~132 MB
    const size_t total_parts  = off_p + DZ * PBYTES;       // ~149 MB

    if (ws_size >= total_atomic) {
        char* ws = (char*)d_ws;
        float* xn2 = (float*)(ws + off_xn2);
        float* kn2 = (float*)(ws + off_kn2);
        u16* x_bf  = (u16*)(ws + off_xbf);
        u16* k_bf  = (u16*)(ws + off_kbf);
        u16* vt    = (u16*)(ws + off_vt);
        u16* kt    = (u16*)(ws + off_kt);
        float* partial = (float*)(ws + off_p);
        const int use_parts = (ws_size >= total_parts);

        prep_x_kernel<<<B_ROWS / 4, 256, 0, stream>>>(x, x_bf, xn2);
        prep_keys_kernel<<<DPAD / 4, 256, 0, stream>>>(keys, k_bf, kn2);
        prep_kt_kernel<<<NCHUNKS, 256, 0, stream>>>(k_bf, kt);
        prep_v_kernel<<<dim3(DPAD / 64, NPAD / 64), 256, 0, stream>>>(V, vt);
        if (!use_parts)
            zero_kernel<<<1024, 256, 0, stream>>>((float4*)partial,
                                                  (int)(PBYTES / 16));
        varkeys_mfma7_kernel<<<dim3(4, 64, DZ), 256, 0, stream>>>(
            kt, x_bf, vt, xn2, kn2, partial, use_parts ? 0 : 1);
        finish_kernel<<<B_ROWS, 256, 0, stream>>>(partial, out, use_parts ? DZ : 1);
    } else {
        float* xn = (float*)d_ws;
        float* kn = xn + B_ROWS;
        row_norm2_kernel<<<B_ROWS / 4, 256, 0, stream>>>(x, xn, B_ROWS);
        row_norm2_kernel<<<D_KEYS / 4 + 1, 256, 0, stream>>>(keys, kn, D_KEYS);
        dim3 grid(4, B_ROWS / BT);
        varkeys_main_kernel<<<grid, 256, 0, stream>>>(x, keys, V, xn, kn, out);
        normalize_kernel<<<B_ROWS, 256, 0, stream>>>(out);
    }
}